// Round 1
// 1157.833 us; speedup vs baseline: 2.0910x; 2.0910x over previous
//
#include <hip/hip_runtime.h>
#include <stdint.h>
#include <math.h>

#define N_ROWS 131072
#define K_CEN  2048
#define D_DIM  1024
#define BM     64
#define TAU    0.02f
#define CAND_CAP 64

typedef short bf16x8 __attribute__((ext_vector_type(8)));
typedef float f32x4  __attribute__((ext_vector_type(4)));

__device__ __forceinline__ unsigned short f2bf(float f) {
  unsigned u = __float_as_uint(f);
  return (unsigned short)((u + 0x7fffu + ((u >> 16) & 1u)) >> 16);  // RNE
}
__device__ __forceinline__ unsigned f2ord(float f) {
  unsigned u = __float_as_uint(f);
  return (u & 0x80000000u) ? ~u : (u | 0x80000000u);  // monotone float->uint
}
__device__ __forceinline__ float ord2f(unsigned o) {
  unsigned u = (o & 0x80000000u) ? (o & 0x7fffffffu) : ~o;
  return __uint_as_float(u);
}

// ---- prep: centroids fp32 -> bf16 (row-major [K][D]) into ws ----
__global__ __launch_bounds__(256) void cvt_centroids(const float* __restrict__ cen,
                                                     unsigned short* __restrict__ outb) {
  int i = blockIdx.x * 256 + threadIdx.x;           // 524288 threads x 4 floats
  float4 v = reinterpret_cast<const float4*>(cen)[i];
  ushort4 r;
  r.x = f2bf(v.x); r.y = f2bf(v.y); r.z = f2bf(v.z); r.w = f2bf(v.w);
  reinterpret_cast<ushort4*>(outb)[i] = r;
}

// ---- main: A resident in LDS; B-frags streamed from L2 into regs; barrier-free K loop.
// Wave w owns cols [w*256, w*256+256) of all 2048, tile 64x64, acc 4x4 of 16x16.
__global__ __launch_bounds__(512, 2) void assign_rows(
    const float* __restrict__ vec, const float* __restrict__ cenf,
    const unsigned short* __restrict__ cenb, int* __restrict__ out)
{
  __shared__ unsigned short v_lds[BM * D_DIM];      // 128 KB, XOR-swizzled bf16
  __shared__ unsigned rowmax_ord[BM];
  __shared__ int cand_cnt[BM];
  __shared__ unsigned candv[BM][CAND_CAP];          // bf16-dot score (ordered uint)
  __shared__ unsigned short candc[BM][CAND_CAP];    // centroid index

  const int tid  = threadIdx.x;
  const int lane = tid & 63;
  const int wid  = tid >> 6;     // 8 waves, each owns a 256-col strip
  const long row0 = (long)blockIdx.x * BM;

  for (int r = tid; r < BM; r += 512) { rowmax_ord[r] = f2ord(-3.0e38f); cand_cnt[r] = 0; }

  // stage v rows -> swizzled bf16 LDS (64 rows x 1024)
  #pragma unroll
  for (int it = 0; it < 16; ++it) {
    int cid = it * 512 + tid;
    int r  = cid >> 7;                 // 128 chunks of 8 per row
    int dc = (cid & 127) << 3;
    const float4* vp = reinterpret_cast<const float4*>(vec + (row0 + r) * D_DIM + dc);
    float4 a = vp[0], b = vp[1];
    bf16x8 pk;
    pk[0]=(short)f2bf(a.x); pk[1]=(short)f2bf(a.y); pk[2]=(short)f2bf(a.z); pk[3]=(short)f2bf(a.w);
    pk[4]=(short)f2bf(b.x); pk[5]=(short)f2bf(b.y); pk[6]=(short)f2bf(b.z); pk[7]=(short)f2bf(b.w);
    int byt = (r << 11) + (dc << 1);
    *reinterpret_cast<bf16x8*>(reinterpret_cast<char*>(v_lds) + (byt ^ ((r & 7) << 4))) = pk;
  }
  __syncthreads();

  const int l15 = lane & 15;
  const int lq  = lane >> 4;
  const int amask = (l15 & 7) << 4;                 // lane-constant XOR swizzle
  const int abase = (l15 << 11) + (lq << 4);        // row(l15)*2048 + oct*16 bytes
  const char* v_bytes = reinterpret_cast<const char*>(v_lds);
  const char* c_bytes = reinterpret_cast<const char*>(cenb);

  for (int cb = 0; cb < 4; ++cb) {
    const int colbase = (wid << 8) + (cb << 6);
    const size_t bbase = ((size_t)(colbase + l15) << 11) + (size_t)(lq << 4);
    const char* bp0 = c_bytes + bbase;              // per-ni base ptrs: k-offset fits imm
    const char* bp1 = bp0 + 32768;
    const char* bp2 = bp1 + 32768;
    const char* bp3 = bp2 + 32768;

    f32x4 acc[4][4];
    #pragma unroll
    for (int mi = 0; mi < 4; ++mi)
      #pragma unroll
      for (int ni = 0; ni < 4; ++ni) acc[mi][ni] = (f32x4){0.f,0.f,0.f,0.f};

    bf16x8 b0[4], b1[4], b2[4], a0[4], a1[4];
    // prologue: b(k=0), b(k=1), a(k=0)
    #pragma unroll
    for (int ni = 0; ni < 4; ++ni) {
      const char* bp = ni==0?bp0: ni==1?bp1: ni==2?bp2: bp3;
      b0[ni] = *reinterpret_cast<const bf16x8*>(bp);
      b1[ni] = *reinterpret_cast<const bf16x8*>(bp + 64);
    }
    {
      int ta = abase ^ amask;
      #pragma unroll
      for (int mi = 0; mi < 4; ++mi)
        a0[mi] = *reinterpret_cast<const bf16x8*>(v_bytes + ta + (mi << 15));
    }

    #pragma unroll
    for (int kc = 0; kc < 32; ++kc) {
      // prefetch B(kc+2) from L2 (depth-2), A(kc+1) from LDS (depth-1)
      const int k2 = (kc + 2 < 32) ? kc + 2 : 31;
      #pragma unroll
      for (int ni = 0; ni < 4; ++ni) {
        const char* bp = ni==0?bp0: ni==1?bp1: ni==2?bp2: bp3;
        b2[ni] = *reinterpret_cast<const bf16x8*>(bp + (k2 << 6));
      }
      const int k1 = (kc + 1 < 32) ? kc + 1 : 31;
      {
        int ta = (abase + (k1 << 6)) ^ amask;
        #pragma unroll
        for (int mi = 0; mi < 4; ++mi)
          a1[mi] = *reinterpret_cast<const bf16x8*>(v_bytes + ta + (mi << 15));
      }

      #pragma unroll
      for (int ni = 0; ni < 4; ++ni)
        #pragma unroll
        for (int mi = 0; mi < 4; ++mi)
          acc[mi][ni] = __builtin_amdgcn_mfma_f32_16x16x32_bf16(a0[mi], b0[ni], acc[mi][ni], 0, 0, 0);

      #pragma unroll
      for (int ni = 0; ni < 4; ++ni) { b0[ni] = b1[ni]; b1[ni] = b2[ni]; }
      #pragma unroll
      for (int mi = 0; mi < 4; ++mi) a0[mi] = a1[mi];
    }

    // running row-max (C layout: col = l15, row = lq*4+j within 16x16 tile)
    #pragma unroll
    for (int mi = 0; mi < 4; ++mi) {
      #pragma unroll
      for (int j = 0; j < 4; ++j) {
        float mv = fmaxf(fmaxf(acc[mi][0][j], acc[mi][1][j]),
                         fmaxf(acc[mi][2][j], acc[mi][3][j]));
        mv = fmaxf(mv, __shfl_xor(mv, 1));
        mv = fmaxf(mv, __shfl_xor(mv, 2));
        mv = fmaxf(mv, __shfl_xor(mv, 4));
        mv = fmaxf(mv, __shfl_xor(mv, 8));
        if (l15 == 0) {
          int row = (mi << 4) + (lq << 2) + j;
          atomicMax(&rowmax_ord[row], f2ord(mv));
        }
      }
    }
    // candidate append (monotone running max => conservative, never misses)
    #pragma unroll
    for (int mi = 0; mi < 4; ++mi) {
      #pragma unroll
      for (int j = 0; j < 4; ++j) {
        int row = (mi << 4) + (lq << 2) + j;
        float thr = ord2f(rowmax_ord[row]) - TAU;
        #pragma unroll
        for (int ni = 0; ni < 4; ++ni) {
          float v = acc[mi][ni][j];
          if (v >= thr) {
            int slot = atomicAdd(&cand_cnt[row], 1);
            if (slot < CAND_CAP) {
              candv[row][slot] = f2ord(v);
              candc[row][slot] = (unsigned short)(colbase + (ni << 4) + l15);
            }
          }
        }
      }
    }
  }
  __syncthreads();

  // filter vs final row max; single survivor => answer directly (no re-read);
  // multiple => exact fp64 rescore, first-occurrence (lowest col) tie-break.
  for (int r = wid; r < BM; r += 8) {
    const long grow = row0 + r;
    int cnt = cand_cnt[r]; cnt = cnt > CAND_CAP ? CAND_CAP : cnt;
    const unsigned thro = f2ord(ord2f(rowmax_ord[r]) - TAU);

    bool sv = (lane < cnt) && (candv[r][lane] >= thro);
    unsigned long long bal = __ballot(sv);
    int nsurv = __popcll(bal);
    if (nsurv == 1) {
      int idx = __builtin_ctzll(bal);
      if (lane == 0) out[grow] = (int)candc[r][idx];
      continue;
    }
    const bool use_filter = (nsurv >= 1);   // nsurv==0 (CAP overflow pathology): rescore all

    const float* vrow = vec + grow * D_DIM + (lane << 4);
    float va[16];
    #pragma unroll
    for (int i = 0; i < 16; ++i) va[i] = vrow[i];
    double bestv = -1.0e300;
    int    besti = 0x7fffffff;
    for (int ci = 0; ci < cnt; ++ci) {
      if (use_filter && candv[r][ci] < thro) continue;
      const int col = (int)candc[r][ci];
      const float* crow = cenf + ((size_t)col << 10) + (lane << 4);
      double s = 0.0;
      #pragma unroll
      for (int i = 0; i < 16; ++i) s = fma((double)va[i], (double)crow[i], s);
      s += __shfl_xor(s, 32);
      s += __shfl_xor(s, 16);
      s += __shfl_xor(s, 8);
      s += __shfl_xor(s, 4);
      s += __shfl_xor(s, 2);
      s += __shfl_xor(s, 1);
      if (s > bestv || (s == bestv && col < besti)) { bestv = s; besti = col; }
    }
    if (lane == 0) out[grow] = besti;
  }
}

extern "C" void kernel_launch(void* const* d_in, const int* in_sizes, int n_in,
                              void* d_out, int out_size, void* d_ws, size_t ws_size,
                              hipStream_t stream) {
  const float* vec  = (const float*)d_in[0];   // [131072][1024] fp32
  const float* cenf = (const float*)d_in[1];   // [2048][1024] fp32 (pre-normalized)
  unsigned short* cenb = (unsigned short*)d_ws; // 4 MB bf16 centroids
  int* out = (int*)d_out;                      // [131072] int32 assignments

  cvt_centroids<<<(K_CEN * D_DIM / 4) / 256, 256, 0, stream>>>(cenf, cenb);
  assign_rows<<<N_ROWS / BM, 512, 0, stream>>>(vec, cenf, cenb, out);
}